// Round 1
// baseline (2414.336 us; speedup 1.0000x reference)
//
#include <hip/hip_runtime.h>

#define VOCAB 50257
#define EMB 256
#define HID 512
#define BATCH 32
#define SEQ 512

// ---------------------------------------------------------------------------
// K1: X[tok][j] = bias[j] + emb[ids[tok]] @ Wx[:,j], written into the all_h
// region of d_out (same shape [B*S][H]). The recurrence kernel later reads
// X[tok][j] and overwrites the slot with h_t[j].
// grid: (B*S/16) blocks x 256 threads. Block: 16 tokens; thread: 2 columns.
// ---------------------------------------------------------------------------
__global__ __launch_bounds__(256) void xprec_kernel(
    const int* __restrict__ ids, const float* __restrict__ emb,
    const float* __restrict__ Wx, const float* __restrict__ bias,
    float* __restrict__ allh)
{
    __shared__ float embL[16][EMB];   // 16 KB
    const int tid  = threadIdx.x;
    const int tok0 = blockIdx.x * 16;

    // Stage 16 embedding rows into LDS: 16 threads per row, 16 floats each.
    {
        const int t    = tid >> 4;    // 0..15 row
        const int part = tid & 15;    // 0..15 -> 16 floats
        const int id   = ids[tok0 + t];
        const float4* src = (const float4*)(emb + (size_t)id * EMB + part * 16);
        float4* dst = (float4*)(&embL[t][part * 16]);
        dst[0] = src[0]; dst[1] = src[1]; dst[2] = src[2]; dst[3] = src[3];
    }
    __syncthreads();

    const int j0 = tid * 2;           // two consecutive columns
    float2 acc[16];
    const float2 bv = *(const float2*)(bias + j0);
#pragma unroll
    for (int t = 0; t < 16; ++t) acc[t] = bv;

    for (int e = 0; e < EMB; e += 4) {
        const float2 w0 = *(const float2*)(Wx + (size_t)(e + 0) * HID + j0);
        const float2 w1 = *(const float2*)(Wx + (size_t)(e + 1) * HID + j0);
        const float2 w2 = *(const float2*)(Wx + (size_t)(e + 2) * HID + j0);
        const float2 w3 = *(const float2*)(Wx + (size_t)(e + 3) * HID + j0);
#pragma unroll
        for (int t = 0; t < 16; ++t) {
            const float4 ev = *(const float4*)(&embL[t][e]);  // LDS broadcast
            acc[t].x += ev.x * w0.x + ev.y * w1.x + ev.z * w2.x + ev.w * w3.x;
            acc[t].y += ev.x * w0.y + ev.y * w1.y + ev.z * w2.y + ev.w * w3.y;
        }
    }

#pragma unroll
    for (int t = 0; t < 16; ++t) {
        *(float2*)(allh + (size_t)(tok0 + t) * HID + j0) = acc[t];
    }
}

// ---------------------------------------------------------------------------
// K2: sequential recurrence, one workgroup per batch (32 blocks x 512 thr).
// Thread j owns hidden column j. h lives in LDS; z_j = (h @ Wh)[j] is cached
// in a register and only recomputed when mask==1 (h changed).
// all_h[b][t][:] initially holds X (from K1) and is overwritten with h_t.
// ---------------------------------------------------------------------------
__global__ __launch_bounds__(512) void rnn_kernel(
    const int* __restrict__ mask, const float* __restrict__ Wh,
    float* __restrict__ allh, float* __restrict__ finalh)
{
    __shared__ float hL[HID];
    const int j = threadIdx.x;
    const int b = blockIdx.x;

    float hreg = 0.f;   // h[b][j]
    float zreg = 0.f;   // (h @ Wh)[j] for current h (h=0 -> z=0)
    hL[j] = 0.f;
    __syncthreads();

    const int*  mrow = mask + b * SEQ;
    float*      arow = allh + (size_t)b * SEQ * HID;
    const float* wcol = Wh + j;

    for (int t = 0; t < SEQ; ++t) {
        float* row = arow + (size_t)t * HID;
        const int m = mrow[t];            // uniform across block
        if (m != 0) {
            const float x = row[j];       // X from K1
            hreg = tanhf(x + zreg);
            // publish new h, then recompute z for the next masked step
            __syncthreads();              // all threads done with old hL
            hL[j] = hreg;
            __syncthreads();              // new hL fully visible
            float a0 = 0.f, a1 = 0.f, a2 = 0.f, a3 = 0.f;
            for (int k = 0; k < HID; k += 8) {
                a0 += hL[k + 0] * wcol[(size_t)(k + 0) * HID];
                a1 += hL[k + 1] * wcol[(size_t)(k + 1) * HID];
                a2 += hL[k + 2] * wcol[(size_t)(k + 2) * HID];
                a3 += hL[k + 3] * wcol[(size_t)(k + 3) * HID];
                a0 += hL[k + 4] * wcol[(size_t)(k + 4) * HID];
                a1 += hL[k + 5] * wcol[(size_t)(k + 5) * HID];
                a2 += hL[k + 6] * wcol[(size_t)(k + 6) * HID];
                a3 += hL[k + 7] * wcol[(size_t)(k + 7) * HID];
            }
            zreg = (a0 + a1) + (a2 + a3);
        }
        row[j] = hreg;                    // h_next (carried h if m==0)
    }
    finalh[b * HID + j] = hreg;
}

extern "C" void kernel_launch(void* const* d_in, const int* in_sizes, int n_in,
                              void* d_out, int out_size, void* d_ws, size_t ws_size,
                              hipStream_t stream) {
    const int*   ids  = (const int*)d_in[0];
    const int*   msk  = (const int*)d_in[1];
    const float* emb  = (const float*)d_in[2];
    const float* Wx   = (const float*)d_in[3];
    const float* Wh   = (const float*)d_in[4];
    const float* bias = (const float*)d_in[5];

    float* allh   = (float*)d_out;                              // [B*S][H]
    float* finalh = (float*)d_out + (size_t)BATCH * SEQ * HID;  // [B][H]

    xprec_kernel<<<BATCH * SEQ / 16, 256, 0, stream>>>(ids, emb, Wx, bias, allh);
    rnn_kernel<<<BATCH, 512, 0, stream>>>(msk, Wh, allh, finalh);
}

// Round 2
// 2138.490 us; speedup vs baseline: 1.1290x; 1.1290x over previous
//
#include <hip/hip_runtime.h>

#define VOCAB 50257
#define EMB 256
#define HID 512
#define BATCH 32
#define SEQ 512
#define G 8          // column slices (workgroups) per batch
#define CPG 64       // columns per slice

// ---------------------------------------------------------------------------
// K1: X[tok][j] = bias[j] + emb[ids[tok]] @ Wx[:,j], written into the all_h
// region of d_out. The recurrence kernel reads X and overwrites with h_t.
// ---------------------------------------------------------------------------
__global__ __launch_bounds__(256) void xprec_kernel(
    const int* __restrict__ ids, const float* __restrict__ emb,
    const float* __restrict__ Wx, const float* __restrict__ bias,
    float* __restrict__ allh)
{
    __shared__ float embL[16][EMB];   // 16 KB
    const int tid  = threadIdx.x;
    const int tok0 = blockIdx.x * 16;

    {
        const int t    = tid >> 4;
        const int part = tid & 15;
        const int id   = ids[tok0 + t];
        const float4* src = (const float4*)(emb + (size_t)id * EMB + part * 16);
        float4* dst = (float4*)(&embL[t][part * 16]);
        dst[0] = src[0]; dst[1] = src[1]; dst[2] = src[2]; dst[3] = src[3];
    }
    __syncthreads();

    const int j0 = tid * 2;
    float2 acc[16];
    const float2 bv = *(const float2*)(bias + j0);
#pragma unroll
    for (int t = 0; t < 16; ++t) acc[t] = bv;

    for (int e = 0; e < EMB; e += 4) {
        const float2 w0 = *(const float2*)(Wx + (size_t)(e + 0) * HID + j0);
        const float2 w1 = *(const float2*)(Wx + (size_t)(e + 1) * HID + j0);
        const float2 w2 = *(const float2*)(Wx + (size_t)(e + 2) * HID + j0);
        const float2 w3 = *(const float2*)(Wx + (size_t)(e + 3) * HID + j0);
#pragma unroll
        for (int t = 0; t < 16; ++t) {
            const float4 ev = *(const float4*)(&embL[t][e]);
            acc[t].x += ev.x * w0.x + ev.y * w1.x + ev.z * w2.x + ev.w * w3.x;
            acc[t].y += ev.x * w0.y + ev.y * w1.y + ev.z * w2.y + ev.w * w3.y;
        }
    }

#pragma unroll
    for (int t = 0; t < 16; ++t) {
        *(float2*)(allh + (size_t)(tok0 + t) * HID + j0) = acc[t];
    }
}

// ---------------------------------------------------------------------------
// K2: recurrence. grid = BATCH*G workgroups of 512 threads; WG (b,g) owns
// columns [g*64, g*64+64) of batch b and holds Wh[:, slice] in REGISTERS
// (wreg[64] per thread; thread (c,p): wreg[kk] = Wh[p*64+kk][g*64+c]).
// Per masked step: z via register FMAs + LDS h broadcasts, then an 8-WG
// per-batch sync through device-scope atomics (double-buffered h in d_ws).
// Unmasked steps touch nothing shared (z is unchanged).
// ---------------------------------------------------------------------------
__global__ __launch_bounds__(512) void rnn_sync_kernel(
    const int* __restrict__ mask, const float* __restrict__ Wh,
    float* __restrict__ allh, float* __restrict__ finalh,
    int* __restrict__ flags, float* __restrict__ hg)
{
    __shared__ float hL[HID];
    __shared__ float zp[G][CPG];
    __shared__ int   maskL[SEQ];

    const int tid = threadIdx.x;
    const int b   = blockIdx.x >> 3;
    const int g   = blockIdx.x & 7;
    const int c   = tid & 63;     // column within slice
    const int p   = tid >> 6;     // k-range 0..7 (64 k's each)

    // Register-resident Wh slice (loaded once; coalesced 256B per kk).
    float wreg[64];
#pragma unroll
    for (int kk = 0; kk < 64; ++kk)
        wreg[kk] = Wh[(size_t)(p * 64 + kk) * HID + (g * 64 + c)];

    hL[tid] = 0.f;
    maskL[tid] = mask[b * SEQ + tid];
    __syncthreads();

    float hreg = 0.f;                 // tid<64: h[b][g*64+tid]
    int   cnt  = 0;                   // masked-step counter (uniform per batch)
    float* arow_base = allh + (size_t)b * SEQ * HID + g * 64;
    int*   bflags    = flags + b * G * 64;          // flag g at bflags[g*64]

    for (int t = 0; t < SEQ; ++t) {
        float* row = arow_base + (size_t)t * HID;
        if (maskL[t] != 0) {
            float x = 0.f;
            if (tid < CPG) x = row[tid];            // issue early (X from K1)

            float acc = 0.f;
#pragma unroll
            for (int kk = 0; kk < 64; ++kk)
                acc += hL[p * 64 + kk] * wreg[kk];  // LDS broadcast * reg
            zp[p][c] = acc;
            __syncthreads();

            const int nb = (cnt + 1) & 1;           // publish buffer parity
            if (tid < CPG) {
                float z = zp[0][tid] + zp[1][tid] + zp[2][tid] + zp[3][tid]
                        + zp[4][tid] + zp[5][tid] + zp[6][tid] + zp[7][tid];
                float hn = tanhf(x + z);
                hreg = hn;
                row[tid] = hn;
                __hip_atomic_store(
                    &hg[((size_t)nb * BATCH + b) * HID + g * 64 + tid], hn,
                    __ATOMIC_RELAXED, __HIP_MEMORY_SCOPE_AGENT);
            }
            __syncthreads();                        // hg stores drained (vmcnt)
            if (tid == 0)
                __hip_atomic_store(&bflags[g * 64], cnt + 1,
                                   __ATOMIC_RELEASE, __HIP_MEMORY_SCOPE_AGENT);
            if (tid < G) {
                while (__hip_atomic_load(&bflags[tid * 64], __ATOMIC_ACQUIRE,
                                         __HIP_MEMORY_SCOPE_AGENT) < cnt + 1) {}
            }
            __syncthreads();
            hL[tid] = __hip_atomic_load(
                &hg[((size_t)nb * BATCH + b) * HID + tid],
                __ATOMIC_RELAXED, __HIP_MEMORY_SCOPE_AGENT);
            cnt = cnt + 1;
            __syncthreads();                        // hL ready for next matvec
        } else {
            if (tid < CPG) row[tid] = hreg;         // h carried
        }
    }
    if (tid < CPG) finalh[b * HID + g * 64 + tid] = hreg;
}

extern "C" void kernel_launch(void* const* d_in, const int* in_sizes, int n_in,
                              void* d_out, int out_size, void* d_ws, size_t ws_size,
                              hipStream_t stream) {
    const int*   ids  = (const int*)d_in[0];
    const int*   msk  = (const int*)d_in[1];
    const float* emb  = (const float*)d_in[2];
    const float* Wx   = (const float*)d_in[3];
    const float* Wh   = (const float*)d_in[4];
    const float* bias = (const float*)d_in[5];

    float* allh   = (float*)d_out;                              // [B*S][H]
    float* finalh = (float*)d_out + (size_t)BATCH * SEQ * HID;  // [B][H]

    // d_ws: [0,64K) per-WG flags (zeroed every launch -> replay-safe),
    //       [64K, 64K+128K) double-buffered h: hg[2][B][H].
    int*   flags = (int*)d_ws;
    float* hg    = (float*)((char*)d_ws + 65536);
    hipMemsetAsync(d_ws, 0, 65536, stream);

    xprec_kernel<<<BATCH * SEQ / 16, 256, 0, stream>>>(ids, emb, Wx, bias, allh);
    // 256 blocks, each fits 1/CU (6KB LDS, <=256 VGPR) on 256 CUs ->
    // all co-resident; per-batch 8-WG flag sync cannot deadlock.
    rnn_sync_kernel<<<BATCH * G, 512, 0, stream>>>(msk, Wh, allh, finalh, flags, hg);
}

// Round 3
// 1932.478 us; speedup vs baseline: 1.2493x; 1.1066x over previous
//
#include <hip/hip_runtime.h>

#define VOCAB 50257
#define EMB 256
#define HID 512
#define BATCH 32
#define SEQ 512
#define G 8          // column slices (workgroups) per batch
#define CPG 64       // columns per slice
#define CTR_STRIDE 64  // ints between per-batch counters (256B lines)

// ---------------------------------------------------------------------------
// K1: X[tok][j] = bias[j] + emb[ids[tok]] @ Wx[:,j], written into the all_h
// region of d_out. The recurrence kernel reads X and overwrites with h_t.
// ---------------------------------------------------------------------------
__global__ __launch_bounds__(256) void xprec_kernel(
    const int* __restrict__ ids, const float* __restrict__ emb,
    const float* __restrict__ Wx, const float* __restrict__ bias,
    float* __restrict__ allh)
{
    __shared__ float embL[16][EMB];   // 16 KB
    const int tid  = threadIdx.x;
    const int tok0 = blockIdx.x * 16;

    {
        const int t    = tid >> 4;
        const int part = tid & 15;
        const int id   = ids[tok0 + t];
        const float4* src = (const float4*)(emb + (size_t)id * EMB + part * 16);
        float4* dst = (float4*)(&embL[t][part * 16]);
        dst[0] = src[0]; dst[1] = src[1]; dst[2] = src[2]; dst[3] = src[3];
    }
    __syncthreads();

    const int j0 = tid * 2;
    float2 acc[16];
    const float2 bv = *(const float2*)(bias + j0);
#pragma unroll
    for (int t = 0; t < 16; ++t) acc[t] = bv;

    for (int e = 0; e < EMB; e += 4) {
        const float2 w0 = *(const float2*)(Wx + (size_t)(e + 0) * HID + j0);
        const float2 w1 = *(const float2*)(Wx + (size_t)(e + 1) * HID + j0);
        const float2 w2 = *(const float2*)(Wx + (size_t)(e + 2) * HID + j0);
        const float2 w3 = *(const float2*)(Wx + (size_t)(e + 3) * HID + j0);
#pragma unroll
        for (int t = 0; t < 16; ++t) {
            const float4 ev = *(const float4*)(&embL[t][e]);
            acc[t].x += ev.x * w0.x + ev.y * w1.x + ev.z * w2.x + ev.w * w3.x;
            acc[t].y += ev.x * w0.y + ev.y * w1.y + ev.z * w2.y + ev.w * w3.y;
        }
    }

#pragma unroll
    for (int t = 0; t < 16; ++t) {
        *(float2*)(allh + (size_t)(tok0 + t) * HID + j0) = acc[t];
    }
}

// ---------------------------------------------------------------------------
// K2: recurrence. grid = BATCH*G WGs x 512 thr; WG (b,g) owns columns
// [g*64,g*64+64) and holds Wh[:, slice] in registers. Per masked step:
// z via LDS-broadcast x register FMAs; publish own h slice (agent-scope
// stores, double-buffered in d_ws); ONE atomicAdd(+1, release) per WG on the
// per-batch counter (lane 0 of the storing wave -> its vmcnt drain covers the
// h stores); one thread polls the counter; reload full h. Only masked steps
// are iterated (compacted list); next X slice prefetched under the poll.
// ---------------------------------------------------------------------------
__global__ __launch_bounds__(512) void rnn_sync_kernel(
    const int* __restrict__ mask, const float* __restrict__ Wh,
    float* __restrict__ allh, float* __restrict__ finalh,
    int* __restrict__ counters, float* __restrict__ hg)
{
    __shared__ float hL[HID];
    __shared__ float zp[G][CPG];
    __shared__ int   maskL[SEQ];
    __shared__ int   mlist[SEQ];
    __shared__ int   nmL;

    const int tid = threadIdx.x;
    const int b   = blockIdx.x >> 3;
    const int g   = blockIdx.x & 7;
    const int c   = tid & 63;     // column within slice
    const int p   = tid >> 6;     // k-range (== wave id; hL reads are uniform)

    // Register-resident Wh slice: wreg[kk] = Wh[p*64+kk][g*64+c]
    float wreg[64];
#pragma unroll
    for (int kk = 0; kk < 64; ++kk)
        wreg[kk] = Wh[(size_t)(p * 64 + kk) * HID + (g * 64 + c)];

    hL[tid] = 0.f;
    maskL[tid] = mask[b * SEQ + tid];
    __syncthreads();
    if (tid == 0) {               // compact masked steps (one-time, ~1us)
        int n = 0;
        for (int t = 0; t < SEQ; ++t) if (maskL[t]) mlist[n++] = t;
        nmL = n;
    }
    __syncthreads();
    const int nm = nmL;

    float* arow_base = allh + (size_t)b * SEQ * HID + g * 64;
    int*   ctr       = counters + b * CTR_STRIDE;

    // rows before the first masked step carry h=0
    {
        const int end0 = nm ? mlist[0] : SEQ;
        if (tid < CPG)
            for (int t = 0; t < end0; ++t)
                arow_base[(size_t)t * HID + tid] = 0.f;
    }

    float hreg = 0.f;
    // prefetch X for the first masked step
    float xnext = 0.f;
    if (nm && tid < CPG) xnext = arow_base[(size_t)mlist[0] * HID + tid];

    for (int i = 0; i < nm; ++i) {
        const int t    = mlist[i];
        const int tend = (i + 1 < nm) ? mlist[i + 1] : SEQ;
        const float x  = xnext;

        // z_partial over this wave's 64 k's (hL read is wave-uniform -> bcast)
        float acc = 0.f;
        const float4* h4 = (const float4*)&hL[p * 64];
#pragma unroll
        for (int q = 0; q < 16; ++q) {
            const float4 hv = h4[q];
            acc += hv.x * wreg[q * 4 + 0] + hv.y * wreg[q * 4 + 1]
                 + hv.z * wreg[q * 4 + 2] + hv.w * wreg[q * 4 + 3];
        }
        zp[p][c] = acc;
        __syncthreads();

        const int par = i & 1;                  // publish buffer parity
        if (tid < CPG) {
            const float z = zp[0][tid] + zp[1][tid] + zp[2][tid] + zp[3][tid]
                          + zp[4][tid] + zp[5][tid] + zp[6][tid] + zp[7][tid];
            const float hn = tanhf(x + z);
            hreg = hn;
            __hip_atomic_store(
                &hg[((size_t)par * BATCH + b) * HID + g * 64 + tid], hn,
                __ATOMIC_RELAXED, __HIP_MEMORY_SCOPE_AGENT);
            if (tid == 0)   // same wave as the stores -> release drains them
                __hip_atomic_fetch_add(ctr, 1, __ATOMIC_RELEASE,
                                       __HIP_MEMORY_SCOPE_AGENT);
        }
        // prefetch next X slice; latency hides under the poll
        if (tid < CPG && i + 1 < nm)
            xnext = arow_base[(size_t)mlist[i + 1] * HID + tid];

        if (tid == 0) {
            while (__hip_atomic_load(ctr, __ATOMIC_ACQUIRE,
                                     __HIP_MEMORY_SCOPE_AGENT) < G * (i + 1)) {}
        }
        __syncthreads();
        hL[tid] = __hip_atomic_load(&hg[((size_t)par * BATCH + b) * HID + tid],
                                    __ATOMIC_RELAXED, __HIP_MEMORY_SCOPE_AGENT);
        __syncthreads();

        // write h for this step + carried (unmasked) rows
        if (tid < CPG)
            for (int tt = t; tt < tend; ++tt)
                arow_base[(size_t)tt * HID + tid] = hreg;
    }
    if (tid < CPG) finalh[b * HID + g * 64 + tid] = hreg;
}

extern "C" void kernel_launch(void* const* d_in, const int* in_sizes, int n_in,
                              void* d_out, int out_size, void* d_ws, size_t ws_size,
                              hipStream_t stream) {
    const int*   ids  = (const int*)d_in[0];
    const int*   msk  = (const int*)d_in[1];
    const float* emb  = (const float*)d_in[2];
    const float* Wx   = (const float*)d_in[3];
    const float* Wh   = (const float*)d_in[4];
    const float* bias = (const float*)d_in[5];

    float* allh   = (float*)d_out;                              // [B*S][H]
    float* finalh = (float*)d_out + (size_t)BATCH * SEQ * HID;  // [B][H]

    // d_ws: [0,64K) per-batch counters (zeroed every launch -> replay-safe),
    //       [64K, 64K+128K) double-buffered h: hg[2][B][H].
    int*   counters = (int*)d_ws;
    float* hg       = (float*)((char*)d_ws + 65536);
    hipMemsetAsync(d_ws, 0, 65536, stream);

    xprec_kernel<<<BATCH * SEQ / 16, 256, 0, stream>>>(ids, emb, Wx, bias, allh);
    // 256 blocks, 1/CU on 256 CUs -> all co-resident; counter sync per batch
    // is monotonic -> no deadlock.
    rnn_sync_kernel<<<BATCH * G, 512, 0, stream>>>(msk, Wh, allh, finalh,
                                                   counters, hg);
}

// Round 4
// 669.838 us; speedup vs baseline: 3.6044x; 2.8850x over previous
//
#include <hip/hip_runtime.h>

#define VOCAB 50257
#define EMB 256
#define HID 512
#define BATCH 32
#define SEQ 512

typedef _Float16 h2 __attribute__((ext_vector_type(2)));

#if __has_builtin(__builtin_amdgcn_fdot2)
#define FDOT2(a, b, c) __builtin_amdgcn_fdot2((a), (b), (c), false)
#else
static __device__ __forceinline__ float FDOT2(h2 a, h2 b, float c) {
    return c + (float)a.x * (float)b.x + (float)a.y * (float)b.y;
}
#endif

static __device__ __forceinline__ h2 mk2(float a, float b) {
    h2 r; r.x = (_Float16)a; r.y = (_Float16)b; return r;
}

// ---------------------------------------------------------------------------
// K1: X[tok][j] = bias[j] + emb[ids[tok]] @ Wx[:,j] -> all_h region of d_out.
// ---------------------------------------------------------------------------
__global__ __launch_bounds__(256) void xprec_kernel(
    const int* __restrict__ ids, const float* __restrict__ emb,
    const float* __restrict__ Wx, const float* __restrict__ bias,
    float* __restrict__ allh)
{
    __shared__ float embL[16][EMB];   // 16 KB
    const int tid  = threadIdx.x;
    const int tok0 = blockIdx.x * 16;

    {
        const int t    = tid >> 4;
        const int part = tid & 15;
        const int id   = ids[tok0 + t];
        const float4* src = (const float4*)(emb + (size_t)id * EMB + part * 16);
        float4* dst = (float4*)(&embL[t][part * 16]);
        dst[0] = src[0]; dst[1] = src[1]; dst[2] = src[2]; dst[3] = src[3];
    }
    __syncthreads();

    const int j0 = tid * 2;
    float2 acc[16];
    const float2 bv = *(const float2*)(bias + j0);
#pragma unroll
    for (int t = 0; t < 16; ++t) acc[t] = bv;

    for (int e = 0; e < EMB; e += 4) {
        const float2 w0 = *(const float2*)(Wx + (size_t)(e + 0) * HID + j0);
        const float2 w1 = *(const float2*)(Wx + (size_t)(e + 1) * HID + j0);
        const float2 w2 = *(const float2*)(Wx + (size_t)(e + 2) * HID + j0);
        const float2 w3 = *(const float2*)(Wx + (size_t)(e + 3) * HID + j0);
#pragma unroll
        for (int t = 0; t < 16; ++t) {
            const float4 ev = *(const float4*)(&embL[t][e]);
            acc[t].x += ev.x * w0.x + ev.y * w1.x + ev.z * w2.x + ev.w * w3.x;
            acc[t].y += ev.x * w0.y + ev.y * w1.y + ev.z * w2.y + ev.w * w3.y;
        }
    }

#pragma unroll
    for (int t = 0; t < 16; ++t) {
        *(float2*)(allh + (size_t)(tok0 + t) * HID + j0) = acc[t];
    }
}

// ---------------------------------------------------------------------------
// K2: one WG per batch, zero cross-WG sync. Thread (c=tid&63, p=tid>>6) owns
// k-range [64p,64p+64) for 8 columns {c+64q}. Wh held on-CU as fp16:
//   q=0..5 in VGPRs (wv*: 192 dwords/thread), q=6,7 in LDS (128 KB).
// Per masked step: packed-fp16 dot2 matvec vs h2L (h as fp16 in LDS),
// partial reduce through zp (16 KB LDS), tanh, 2 __syncthreads. Only masked
// steps iterate (compacted list); carried rows written in runs; next X row
// prefetched under the matvec.
// ---------------------------------------------------------------------------
__global__ __launch_bounds__(512, 2) void rnn_local_kernel(
    const int* __restrict__ mask, const float* __restrict__ Wh,
    float* __restrict__ allh, float* __restrict__ finalh)
{
    __shared__ h2    wlds[2][32][512];   // 128 KB, cols q=6,7
    __shared__ float zp[8][8][64];       // 16 KB (aliased as mask staging)
    __shared__ h2    h2L[256];           // 1 KB packed h (512 halves)
    __shared__ int   mlist[SEQ];         // 2 KB
    __shared__ int   nmL;

    const int tid = threadIdx.x;
    const int b   = blockIdx.x;
    const int c   = tid & 63;
    const int p   = tid >> 6;

    // ---- mask compaction (stage mask in zp's storage; zp unused yet) ----
    int* maskL = (int*)zp;
    maskL[tid] = mask[b * SEQ + tid];
    __syncthreads();
    if (tid == 0) {
        int n = 0;
        for (int t = 0; t < SEQ; ++t) if (maskL[t]) mlist[n++] = t;
        nmL = n;
    }

    // ---- load Wh slice as fp16 (pairs along k): wv?[i] = (W[64p+2i][c+64q],
    //      W[64p+2i+1][c+64q]) ----
    const float* wb = Wh + (size_t)(64 * p) * HID + c;
    h2 wv0[32], wv1[32], wv2[32], wv3[32], wv4[32], wv5[32];
#pragma unroll
    for (int i = 0; i < 32; ++i) {
        const float* r0 = wb + (size_t)(2 * i) * HID;
        const float* r1 = r0 + HID;
        wv0[i] = mk2(r0[0 * 64], r1[0 * 64]);
        wv1[i] = mk2(r0[1 * 64], r1[1 * 64]);
        wv2[i] = mk2(r0[2 * 64], r1[2 * 64]);
        wv3[i] = mk2(r0[3 * 64], r1[3 * 64]);
        wv4[i] = mk2(r0[4 * 64], r1[4 * 64]);
        wv5[i] = mk2(r0[5 * 64], r1[5 * 64]);
        wlds[0][i][tid] = mk2(r0[6 * 64], r1[6 * 64]);
        wlds[1][i][tid] = mk2(r0[7 * 64], r1[7 * 64]);
    }
    if (tid < 256) h2L[tid] = mk2(0.f, 0.f);

    __syncthreads();                 // mlist/nm + wlds + h2L ready
    const int nm = nmL;

    float* arow = allh + (size_t)b * SEQ * HID;

    // rows before the first masked step carry h = 0
    {
        const int end0 = nm ? mlist[0] : SEQ;
        for (int t = 0; t < end0; ++t) arow[(size_t)t * HID + tid] = 0.f;
    }

    float hreg  = 0.f;
    float xnext = 0.f;
    if (nm) xnext = arow[(size_t)mlist[0] * HID + tid];

    for (int i = 0; i < nm; ++i) {
        const int t    = mlist[i];
        const int tend = (i + 1 < nm) ? mlist[i + 1] : SEQ;
        const float x  = xnext;
        if (i + 1 < nm)              // prefetch next X row; hides under matvec
            xnext = arow[(size_t)mlist[i + 1] * HID + tid];

        float a0 = 0.f, a1 = 0.f, a2 = 0.f, a3 = 0.f;
        float a4 = 0.f, a5 = 0.f, a6 = 0.f, a7 = 0.f;
        const h2* hp = &h2L[32 * p];     // wave-uniform -> LDS broadcast
#pragma unroll
        for (int i2 = 0; i2 < 32; ++i2) {
            const h2 hv = hp[i2];
            a0 = FDOT2(wv0[i2], hv, a0);
            a1 = FDOT2(wv1[i2], hv, a1);
            a2 = FDOT2(wv2[i2], hv, a2);
            a3 = FDOT2(wv3[i2], hv, a3);
            a4 = FDOT2(wv4[i2], hv, a4);
            a5 = FDOT2(wv5[i2], hv, a5);
            a6 = FDOT2(wlds[0][i2][tid], hv, a6);
            a7 = FDOT2(wlds[1][i2][tid], hv, a7);
        }
        zp[p][0][c] = a0; zp[p][1][c] = a1; zp[p][2][c] = a2; zp[p][3][c] = a3;
        zp[p][4][c] = a4; zp[p][5][c] = a5; zp[p][6][c] = a6; zp[p][7][c] = a7;
        __syncthreads();

        // thread tid == column j: reduce 8 partials, tanh, publish
        const float z = zp[0][p][c] + zp[1][p][c] + zp[2][p][c] + zp[3][p][c]
                      + zp[4][p][c] + zp[5][p][c] + zp[6][p][c] + zp[7][p][c];
        const float hn = tanhf(x + z);
        hreg = hn;
        ((_Float16*)h2L)[tid] = (_Float16)hn;
        for (int tt = t; tt < tend; ++tt)        // this step + carried run
            arow[(size_t)tt * HID + tid] = hreg;
        __syncthreads();                         // h2L ready for next matvec
    }
    finalh[b * HID + tid] = hreg;
}

extern "C" void kernel_launch(void* const* d_in, const int* in_sizes, int n_in,
                              void* d_out, int out_size, void* d_ws, size_t ws_size,
                              hipStream_t stream) {
    const int*   ids  = (const int*)d_in[0];
    const int*   msk  = (const int*)d_in[1];
    const float* emb  = (const float*)d_in[2];
    const float* Wx   = (const float*)d_in[3];
    const float* Wh   = (const float*)d_in[4];
    const float* bias = (const float*)d_in[5];

    float* allh   = (float*)d_out;                              // [B*S][H]
    float* finalh = (float*)d_out + (size_t)BATCH * SEQ * HID;  // [B][H]

    xprec_kernel<<<BATCH * SEQ / 16, 256, 0, stream>>>(ids, emb, Wx, bias, allh);
    // 32 WGs, one per batch, one per CU; intra-WG sync only -> no fabric
    // round trips, no workspace, no deadlock surface.
    rnn_local_kernel<<<BATCH, 512, 0, stream>>>(msk, Wh, allh, finalh);
}